// Round 4
// baseline (580.882 us; speedup 1.0000x reference)
//
#include <hip/hip_runtime.h>
#include <hip/hip_bf16.h>

#define B_ 4
#define S_ 2048
#define D_ 1024
#define F_ 4096

typedef short bf16x8 __attribute__((ext_vector_type(8)));
typedef float f32x4 __attribute__((ext_vector_type(4)));

static __device__ __forceinline__ unsigned short f2bf(float f) {
    union { float f; unsigned int u; } v; v.f = f;
    unsigned int u = v.u + 0x7FFF + ((v.u >> 16) & 1);  // RNE
    return (unsigned short)(u >> 16);
}
static __device__ __forceinline__ float bf2f(unsigned short u) {
    union { unsigned int u; float f; } v; v.u = ((unsigned int)u) << 16;
    return v.f;
}

// async global->LDS, 16B per lane. LDS dest is wave-uniform base + lane*16.
typedef const __attribute__((address_space(1))) unsigned int* gp_t;
typedef __attribute__((address_space(3))) unsigned int* lp_t;
static __device__ __forceinline__ void gld16(const unsigned short* g, unsigned short* l) {
    __builtin_amdgcn_global_load_lds((gp_t)g, (lp_t)l, 16, 0, 0);
}

// ---------------- transpose fp32 (R x C) -> bf16 (C x R) ----------------
__global__ __launch_bounds__(256) void k_transpose_f32_bf16(
    const float* __restrict__ in, unsigned short* __restrict__ out, int R, int C) {
    __shared__ float t[32][33];
    int c0 = blockIdx.x * 32, r0 = blockIdx.y * 32;
    int x = threadIdx.x, y = threadIdx.y;  // 32 x 8
#pragma unroll
    for (int i = 0; i < 4; i++)
        t[y + 8 * i][x] = in[(size_t)(r0 + y + 8 * i) * C + c0 + x];
    __syncthreads();
#pragma unroll
    for (int i = 0; i < 4; i++)
        out[(size_t)(c0 + y + 8 * i) * R + r0 + x] = f2bf(t[x][y + 8 * i]);
}

// QKV weight transposes fused: z picks source, writes QKVwT + z*D*D (each D x D)
__global__ __launch_bounds__(256) void k_transpose_w3(
    const float* __restrict__ Qw, const float* __restrict__ Kw, const float* __restrict__ Vw,
    unsigned short* __restrict__ out) {
    __shared__ float t[32][33];
    int z = blockIdx.z;
    const float* in = (z == 0) ? Qw : (z == 1) ? Kw : Vw;
    out += (size_t)z * D_ * D_;
    int c0 = blockIdx.x * 32, r0 = blockIdx.y * 32;
    int x = threadIdx.x, y = threadIdx.y;
#pragma unroll
    for (int i = 0; i < 4; i++)
        t[y + 8 * i][x] = in[(size_t)(r0 + y + 8 * i) * D_ + c0 + x];
    __syncthreads();
#pragma unroll
    for (int i = 0; i < 4; i++)
        out[(size_t)(c0 + y + 8 * i) * D_ + r0 + x] = f2bf(t[x][y + 8 * i]);
}

// ---------------- strided bf16 transpose: in (R x C, ldin, batch szin) -> out (C x R, ldout, szout)
__global__ __launch_bounds__(256) void k_transpose_bf16(
    const unsigned short* __restrict__ in, unsigned short* __restrict__ out,
    int ldin, int ldout, long long szin, long long szout) {
    __shared__ unsigned short t[32][33];
    in += (long long)blockIdx.z * szin;
    out += (long long)blockIdx.z * szout;
    int c0 = blockIdx.x * 32, r0 = blockIdx.y * 32;
    int x = threadIdx.x, y = threadIdx.y;
#pragma unroll
    for (int i = 0; i < 4; i++)
        t[y + 8 * i][x] = in[(size_t)(r0 + y + 8 * i) * ldin + c0 + x];
    __syncthreads();
#pragma unroll
    for (int i = 0; i < 4; i++)
        out[(size_t)(c0 + y + 8 * i) * ldout + r0 + x] = t[x][y + 8 * i];
}

// ---------------- layernorm: fp32 row (D_) -> bf16 row ----------------
__global__ __launch_bounds__(256) void k_layernorm(
    const float* __restrict__ x, const float* __restrict__ gamma,
    const float* __restrict__ beta, unsigned short* __restrict__ out) {
    int row = blockIdx.x;
    int t = threadIdx.x;
    const float* xr = x + (size_t)row * D_;
    float4 v = ((const float4*)xr)[t];
    float s = v.x + v.y + v.z + v.w;
    float q = v.x * v.x + v.y * v.y + v.z * v.z + v.w * v.w;
#pragma unroll
    for (int off = 32; off; off >>= 1) {
        s += __shfl_down(s, off);
        q += __shfl_down(q, off);
    }
    __shared__ float ls[4], lq[4];
    int wv = t >> 6;
    if ((t & 63) == 0) { ls[wv] = s; lq[wv] = q; }
    __syncthreads();
    if (t == 0) {
        float S = ls[0] + ls[1] + ls[2] + ls[3];
        float Q = lq[0] + lq[1] + lq[2] + lq[3];
        float mean = S * (1.0f / D_);
        float var = Q * (1.0f / D_) - mean * mean;
        ls[0] = mean; lq[0] = rsqrtf(var + 1e-5f);
    }
    __syncthreads();
    float mean = ls[0], rstd = lq[0];
    float4 g = ((const float4*)gamma)[t];
    float4 b = ((const float4*)beta)[t];
    ushort4 o;
    o.x = f2bf(g.x * (v.x - mean) * rstd + b.x);
    o.y = f2bf(g.y * (v.y - mean) * rstd + b.y);
    o.z = f2bf(g.z * (v.z - mean) * rstd + b.z);
    o.w = f2bf(g.w * (v.w - mean) * rstd + b.w);
    ((ushort4*)(out + (size_t)row * D_))[t] = o;
}

// ---------------- causal softmax, in-place on bf16 scores rows ----------------
__global__ __launch_bounds__(256) void k_softmax(unsigned short* __restrict__ sp) {
    int r = blockIdx.x;          // global row in [0, B_*S_)
    int i = r & (S_ - 1);        // query index within batch
    unsigned short* row = sp + (size_t)r * S_;
    int t = threadIdx.x;
    int valid = i + 1;
    float vals[8];
    float mx = -1e30f;
#pragma unroll
    for (int k = 0; k < 8; k++) {
        int j = t + k * 256;
        vals[k] = (j < valid) ? bf2f(row[j]) : -1e30f;
        mx = fmaxf(mx, vals[k]);
    }
#pragma unroll
    for (int off = 32; off; off >>= 1) mx = fmaxf(mx, __shfl_xor(mx, off));
    __shared__ float red[4];
    if ((t & 63) == 0) red[t >> 6] = mx;
    __syncthreads();
    mx = fmaxf(fmaxf(red[0], red[1]), fmaxf(red[2], red[3]));
    __syncthreads();
    float e[8];
    float sum = 0.f;
#pragma unroll
    for (int k = 0; k < 8; k++) {
        int j = t + k * 256;
        e[k] = (j < valid) ? __expf(vals[k] - mx) : 0.f;
        sum += e[k];
    }
#pragma unroll
    for (int off = 32; off; off >>= 1) sum += __shfl_xor(sum, off);
    if ((t & 63) == 0) red[t >> 6] = sum;
    __syncthreads();
    sum = red[0] + red[1] + red[2] + red[3];
    float inv = 1.0f / sum;
#pragma unroll
    for (int k = 0; k < 8; k++) {
        int j = t + k * 256;
        row[j] = f2bf(e[k] * inv);
    }
}

// ---------------- reduce: out += p0 + p1 + b2 (split-K combine) ----------------
__global__ __launch_bounds__(256) void k_addreduce(
    float* __restrict__ out, const unsigned short* __restrict__ p0,
    const unsigned short* __restrict__ p1, const float* __restrict__ b2) {
    size_t i = (size_t)blockIdx.x * 1024 + threadIdx.x * 4;  // 4 floats per thread
    float4 o = *(const float4*)(out + i);
    ushort4 a = *(const ushort4*)(p0 + i);
    ushort4 b = *(const ushort4*)(p1 + i);
    int c = (int)(i & (D_ - 1));  // column within row
    float4 bias = *(const float4*)(b2 + c);
    o.x += bf2f(a.x) + bf2f(b.x) + bias.x;
    o.y += bf2f(a.y) + bf2f(b.y) + bias.y;
    o.z += bf2f(a.z) + bf2f(b.z) + bias.z;
    o.w += bf2f(a.w) + bf2f(b.w) + bias.w;
    *(float4*)(out + i) = o;
}

// ---------------- GEMM: C = A(MxK) @ Bt(NxK)^T, bf16 in, fp32 accum ----------------
// 128x128 tile, 256 threads / 4 waves, m97 structure (global_load_lds w=16).
// EPI: 0 = bf16 store; 1 = bf16 store * scale, skip blocks fully above diag;
//      2 = fp32 store + res; 3 = bf16 store relu(acc + bias[n]);
//      4 = fp32 store acc + bias[n] + res
// Split-K usage: pass per-split K, sA=sB=K_split (shifts the K window by z),
// sC = partial-buffer stride; EPI=0 stores bf16 partials.
template <int EPI>
__global__ __launch_bounds__(256) void k_gemm_bt(
    const unsigned short* __restrict__ A, const unsigned short* __restrict__ Bt,
    void* __restrict__ Cv, const float* __restrict__ bias, const float* __restrict__ res,
    int K, int lda, int ldb, int ldc,
    long long sA, long long sB, long long sC, float scale, int klimit) {
    int bn = blockIdx.x, bm = blockIdx.y, z = blockIdx.z;
    if (EPI == 1 && bn > bm) return;  // fully-masked causal block
    A += (long long)z * sA;
    Bt += (long long)z * sB;
    long long coff = (long long)z * sC;
    float* Cf = (float*)Cv;
    unsigned short* Cb = (unsigned short*)Cv;

    __shared__ unsigned short As[128 * 32];  // unpadded: required by global_load_lds lane order
    __shared__ unsigned short Bs[128 * 32];

    int t = threadIdx.x;
    int l = t & 63, w = t >> 6;
    int wm = (w & 1) * 64, wn = (w >> 1) * 64;
    int lr = l & 15, lq = l >> 4;

    f32x4 acc[4][4];
#pragma unroll
    for (int i = 0; i < 4; i++)
#pragma unroll
        for (int j = 0; j < 4; j++) acc[i][j] = (f32x4){0.f, 0.f, 0.f, 0.f};

    int kend = K;
    if (klimit) { int ke = (bm + 1) * 128; kend = ke < K ? ke : K; }

    // staging: wave w covers tile rows [w*32, w*32+32); lane l -> row w*32+(l>>2),
    // k-cols (l&3)*8..+8. LDS chunk base (wave-uniform) + l*16B == row-major 128x32.
    int sr = l >> 2;
    int sc = (l & 3) * 8;
    const unsigned short* gA0 = A + (size_t)(bm * 128 + w * 32 + sr) * lda + sc;
    const unsigned short* gA1 = gA0 + (size_t)16 * lda;
    const unsigned short* gB0 = Bt + (size_t)(bn * 128 + w * 32 + sr) * ldb + sc;
    const unsigned short* gB1 = gB0 + (size_t)16 * ldb;
    unsigned short* lA0 = &As[(w * 32) * 32];
    unsigned short* lA1 = &As[(w * 32 + 16) * 32];
    unsigned short* lB0 = &Bs[(w * 32) * 32];
    unsigned short* lB1 = &Bs[(w * 32 + 16) * 32];

    for (int k0 = 0; k0 < kend; k0 += 32) {
        __syncthreads();  // previous iteration's LDS reads done before overwrite
        gld16(gA0 + k0, lA0);
        gld16(gA1 + k0, lA1);
        gld16(gB0 + k0, lB0);
        gld16(gB1 + k0, lB1);
        __syncthreads();  // vmcnt(0) drained before barrier -> LDS valid
        bf16x8 af[4], bf[4];
#pragma unroll
        for (int i = 0; i < 4; i++)
            af[i] = *(const bf16x8*)(&As[(wm + i * 16 + lr) * 32 + lq * 8]);
#pragma unroll
        for (int j = 0; j < 4; j++)
            bf[j] = *(const bf16x8*)(&Bs[(wn + j * 16 + lr) * 32 + lq * 8]);
#pragma unroll
        for (int i = 0; i < 4; i++)
#pragma unroll
            for (int j = 0; j < 4; j++)
                acc[i][j] = __builtin_amdgcn_mfma_f32_16x16x32_bf16(af[i], bf[j], acc[i][j], 0, 0, 0);
    }

#pragma unroll
    for (int i = 0; i < 4; i++) {
        int mbase = bm * 128 + wm + i * 16 + lq * 4;
#pragma unroll
        for (int j = 0; j < 4; j++) {
            int n = bn * 128 + wn + j * 16 + lr;
#pragma unroll
            for (int r = 0; r < 4; r++) {
                int m = mbase + r;
                float v = acc[i][j][r];
                long long idx = coff + (long long)m * ldc + n;
                if (EPI == 0) {
                    Cb[idx] = f2bf(v);
                } else if (EPI == 1) {
                    Cb[idx] = f2bf(v * scale);
                } else if (EPI == 2) {
                    Cf[idx] = v + res[idx];
                } else if (EPI == 3) {
                    float u = v + bias[n];
                    Cb[idx] = f2bf(u > 0.f ? u : 0.f);
                } else {  // EPI == 4
                    Cf[idx] = v + bias[n] + res[idx];
                }
            }
        }
    }
}

extern "C" void kernel_launch(void* const* d_in, const int* in_sizes, int n_in,
                              void* d_out, int out_size, void* d_ws, size_t ws_size,
                              hipStream_t stream) {
    const float* x      = (const float*)d_in[0];
    const float* Qw     = (const float*)d_in[1];
    const float* Kw     = (const float*)d_in[2];
    const float* Vw     = (const float*)d_in[3];
    const float* w1     = (const float*)d_in[4];
    const float* b1     = (const float*)d_in[5];
    const float* w2     = (const float*)d_in[6];
    const float* b2     = (const float*)d_in[7];
    const float* gamma1 = (const float*)d_in[8];
    const float* beta1  = (const float*)d_in[9];
    const float* gamma2 = (const float*)d_in[10];
    const float* beta2  = (const float*)d_in[11];
    float* out = (float*)d_out;

    char* ws = (char*)d_ws;
    size_t off = 0;
    auto alloc = [&](size_t bytes) -> void* {
        void* p = ws + off;
        off += (bytes + 255) & ~(size_t)255;
        return p;
    };
    const size_t MN = (size_t)B_ * S_ * D_;  // 8.4M elems
    unsigned short* xn     = (unsigned short*)alloc(MN * 2);                     // 16.8MB
    unsigned short* scoreP = (unsigned short*)alloc((size_t)B_ * S_ * S_ * 2);   // 33.6MB, scores->P in place
    unsigned short* qkv    = (unsigned short*)alloc((size_t)B_ * S_ * 3072 * 2); // 50.3MB interleaved Q|K|V
    unsigned short* VT     = (unsigned short*)alloc(MN * 2);                     // 16.8MB
    unsigned short* QKVwT  = (unsigned short*)alloc((size_t)3 * D_ * D_ * 2);    // 6.3MB
    unsigned short* w1T    = (unsigned short*)alloc((size_t)D_ * F_ * 2);        // 8.4MB
    unsigned short* w2T    = (unsigned short*)alloc((size_t)F_ * D_ * 2);        // 8.4MB
    // mid (8192 x 4096 bf16 = 67,108,864 B) overlays qkv+VT (dead after PV).
    unsigned short* mid = qkv;
    // split-K partials (2 x MN bf16 = 33,554,432 B) overlay scoreP (dead after PV). Exact fit.
    unsigned short* part = scoreP;

    dim3 tb(32, 8);
    // weight conversion (transposed so all GEMMs take Bt = N x K)
    k_transpose_w3<<<dim3(D_ / 32, D_ / 32, 3), tb, 0, stream>>>(Qw, Kw, Vw, QKVwT);
    k_transpose_f32_bf16<<<dim3(F_ / 32, D_ / 32), tb, 0, stream>>>(w1, w1T, D_, F_);
    k_transpose_f32_bf16<<<dim3(D_ / 32, F_ / 32), tb, 0, stream>>>(w2, w2T, F_, D_);

    // LN1
    k_layernorm<<<B_ * S_, 256, 0, stream>>>(x, gamma1, beta1, xn);

    // fused QKV projection: M = 8192, N = 3072, K = 1024 -> qkv row-major (ldc 3072)
    const int Mtok = B_ * S_;
    k_gemm_bt<0><<<dim3(3072 / 128, Mtok / 128), 256, 0, stream>>>(
        xn, QKVwT, qkv, nullptr, nullptr, D_, D_, D_, 3072, 0, 0, 0, 1.f, 0);

    // V transpose per batch: (S x D, ld 3072) -> VT (D x S)
    k_transpose_bf16<<<dim3(D_ / 32, S_ / 32, B_), tb, 0, stream>>>(
        qkv + 2048, VT, 3072, S_, (long long)S_ * 3072, (long long)D_ * S_);

    // scores = Q @ K^T / 32 (batched, bf16 out), upper-tri blocks skipped
    k_gemm_bt<1><<<dim3(S_ / 128, S_ / 128, B_), 256, 0, stream>>>(
        qkv, qkv + 1024, scoreP, nullptr, nullptr, D_, 3072, 3072, S_,
        (long long)S_ * 3072, (long long)S_ * 3072, (long long)S_ * S_, 0.03125f, 0);

    // causal softmax in place -> P (bf16)
    k_softmax<<<B_ * S_, 256, 0, stream>>>(scoreP);

    // attn = P @ V + x -> out (fp32); K-loop truncated at diagonal
    k_gemm_bt<2><<<dim3(D_ / 128, S_ / 128, B_), 256, 0, stream>>>(
        scoreP, VT, out, nullptr, x, S_, S_, S_, D_,
        (long long)S_ * S_, (long long)D_ * S_, (long long)S_ * D_, 1.f, 1);

    // LN2 on out -> xn (h)
    k_layernorm<<<B_ * S_, 256, 0, stream>>>(out, gamma2, beta2, xn);

    // mid = relu(h @ w1 + b1) (bf16)
    k_gemm_bt<3><<<dim3(F_ / 128, Mtok / 128), 256, 0, stream>>>(
        xn, w1T, mid, b1, nullptr, D_, D_, D_, F_, 0, 0, 0, 1.f, 0);

    // MLP2 split-K=2: partials (bf16) = mid @ w2, z shifts K-window by 2048
    k_gemm_bt<0><<<dim3(D_ / 128, Mtok / 128, 2), 256, 0, stream>>>(
        mid, w2T, part, nullptr, nullptr, F_ / 2, F_, F_, D_,
        F_ / 2, F_ / 2, (long long)MN, 1.f, 0);

    // out += p0 + p1 + b2
    k_addreduce<<<(int)(MN / 1024), 256, 0, stream>>>(out, part, part + MN, b2);
}

// Round 5
// 562.589 us; speedup vs baseline: 1.0325x; 1.0325x over previous
//
#include <hip/hip_runtime.h>
#include <hip/hip_bf16.h>

#define B_ 4
#define S_ 2048
#define D_ 1024
#define F_ 4096

typedef short bf16x8 __attribute__((ext_vector_type(8)));
typedef float f32x4 __attribute__((ext_vector_type(4)));

static __device__ __forceinline__ unsigned short f2bf(float f) {
    union { float f; unsigned int u; } v; v.f = f;
    unsigned int u = v.u + 0x7FFF + ((v.u >> 16) & 1);  // RNE
    return (unsigned short)(u >> 16);
}
static __device__ __forceinline__ float bf2f(unsigned short u) {
    union { unsigned int u; float f; } v; v.u = ((unsigned int)u) << 16;
    return v.f;
}

// async global->LDS, 16B per lane. LDS dest is wave-uniform base + lane*16.
typedef const __attribute__((address_space(1))) unsigned int* gp_t;
typedef __attribute__((address_space(3))) unsigned int* lp_t;
static __device__ __forceinline__ void gld16(const unsigned short* g, unsigned short* l) {
    __builtin_amdgcn_global_load_lds((gp_t)g, (lp_t)l, 16, 0, 0);
}

// ---------------- transpose fp32 (R x C) -> bf16 (C x R) ----------------
__global__ __launch_bounds__(256) void k_transpose_f32_bf16(
    const float* __restrict__ in, unsigned short* __restrict__ out, int R, int C) {
    __shared__ float t[32][33];
    int c0 = blockIdx.x * 32, r0 = blockIdx.y * 32;
    int x = threadIdx.x, y = threadIdx.y;  // 32 x 8
#pragma unroll
    for (int i = 0; i < 4; i++)
        t[y + 8 * i][x] = in[(size_t)(r0 + y + 8 * i) * C + c0 + x];
    __syncthreads();
#pragma unroll
    for (int i = 0; i < 4; i++)
        out[(size_t)(c0 + y + 8 * i) * R + r0 + x] = f2bf(t[x][y + 8 * i]);
}

// QKV weight transposes fused: z picks source, writes QKVwT + z*D*D (each D x D)
__global__ __launch_bounds__(256) void k_transpose_w3(
    const float* __restrict__ Qw, const float* __restrict__ Kw, const float* __restrict__ Vw,
    unsigned short* __restrict__ out) {
    __shared__ float t[32][33];
    int z = blockIdx.z;
    const float* in = (z == 0) ? Qw : (z == 1) ? Kw : Vw;
    out += (size_t)z * D_ * D_;
    int c0 = blockIdx.x * 32, r0 = blockIdx.y * 32;
    int x = threadIdx.x, y = threadIdx.y;
#pragma unroll
    for (int i = 0; i < 4; i++)
        t[y + 8 * i][x] = in[(size_t)(r0 + y + 8 * i) * D_ + c0 + x];
    __syncthreads();
#pragma unroll
    for (int i = 0; i < 4; i++)
        out[(size_t)(c0 + y + 8 * i) * D_ + r0 + x] = f2bf(t[x][y + 8 * i]);
}

// ---------------- strided bf16 transpose: in (R x C, ldin, batch szin) -> out (C x R, ldout, szout)
__global__ __launch_bounds__(256) void k_transpose_bf16(
    const unsigned short* __restrict__ in, unsigned short* __restrict__ out,
    int ldin, int ldout, long long szin, long long szout) {
    __shared__ unsigned short t[32][33];
    in += (long long)blockIdx.z * szin;
    out += (long long)blockIdx.z * szout;
    int c0 = blockIdx.x * 32, r0 = blockIdx.y * 32;
    int x = threadIdx.x, y = threadIdx.y;
#pragma unroll
    for (int i = 0; i < 4; i++)
        t[y + 8 * i][x] = in[(size_t)(r0 + y + 8 * i) * ldin + c0 + x];
    __syncthreads();
#pragma unroll
    for (int i = 0; i < 4; i++)
        out[(size_t)(c0 + y + 8 * i) * ldout + r0 + x] = t[x][y + 8 * i];
}

// ---------------- layernorm: fp32 row (D_) -> bf16 row ----------------
__global__ __launch_bounds__(256) void k_layernorm(
    const float* __restrict__ x, const float* __restrict__ gamma,
    const float* __restrict__ beta, unsigned short* __restrict__ out) {
    int row = blockIdx.x;
    int t = threadIdx.x;
    const float* xr = x + (size_t)row * D_;
    float4 v = ((const float4*)xr)[t];
    float s = v.x + v.y + v.z + v.w;
    float q = v.x * v.x + v.y * v.y + v.z * v.z + v.w * v.w;
#pragma unroll
    for (int off = 32; off; off >>= 1) {
        s += __shfl_down(s, off);
        q += __shfl_down(q, off);
    }
    __shared__ float ls[4], lq[4];
    int wv = t >> 6;
    if ((t & 63) == 0) { ls[wv] = s; lq[wv] = q; }
    __syncthreads();
    if (t == 0) {
        float S = ls[0] + ls[1] + ls[2] + ls[3];
        float Q = lq[0] + lq[1] + lq[2] + lq[3];
        float mean = S * (1.0f / D_);
        float var = Q * (1.0f / D_) - mean * mean;
        ls[0] = mean; lq[0] = rsqrtf(var + 1e-5f);
    }
    __syncthreads();
    float mean = ls[0], rstd = lq[0];
    float4 g = ((const float4*)gamma)[t];
    float4 b = ((const float4*)beta)[t];
    ushort4 o;
    o.x = f2bf(g.x * (v.x - mean) * rstd + b.x);
    o.y = f2bf(g.y * (v.y - mean) * rstd + b.y);
    o.z = f2bf(g.z * (v.z - mean) * rstd + b.z);
    o.w = f2bf(g.w * (v.w - mean) * rstd + b.w);
    ((ushort4*)(out + (size_t)row * D_))[t] = o;
}

// ---------------- causal softmax, in-place on bf16 scores rows ----------------
__global__ __launch_bounds__(256) void k_softmax(unsigned short* __restrict__ sp) {
    int r = blockIdx.x;          // global row in [0, B_*S_)
    int i = r & (S_ - 1);        // query index within batch
    unsigned short* row = sp + (size_t)r * S_;
    int t = threadIdx.x;
    int valid = i + 1;
    float vals[8];
    float mx = -1e30f;
#pragma unroll
    for (int k = 0; k < 8; k++) {
        int j = t + k * 256;
        vals[k] = (j < valid) ? bf2f(row[j]) : -1e30f;
        mx = fmaxf(mx, vals[k]);
    }
#pragma unroll
    for (int off = 32; off; off >>= 1) mx = fmaxf(mx, __shfl_xor(mx, off));
    __shared__ float red[4];
    if ((t & 63) == 0) red[t >> 6] = mx;
    __syncthreads();
    mx = fmaxf(fmaxf(red[0], red[1]), fmaxf(red[2], red[3]));
    __syncthreads();
    float e[8];
    float sum = 0.f;
#pragma unroll
    for (int k = 0; k < 8; k++) {
        int j = t + k * 256;
        e[k] = (j < valid) ? __expf(vals[k] - mx) : 0.f;
        sum += e[k];
    }
#pragma unroll
    for (int off = 32; off; off >>= 1) sum += __shfl_xor(sum, off);
    if ((t & 63) == 0) red[t >> 6] = sum;
    __syncthreads();
    sum = red[0] + red[1] + red[2] + red[3];
    float inv = 1.0f / sum;
#pragma unroll
    for (int k = 0; k < 8; k++) {
        int j = t + k * 256;
        row[j] = f2bf(e[k] * inv);
    }
}

// ---------------- GEMM: C = A(MxK) @ Bt(NxK)^T, bf16 in, fp32 accum ----------------
// 128x128 tile, 256 threads / 4 waves, m97 structure (global_load_lds w=16).
// XCD-aware swizzle (swz = XB = bn-groups across the 8 XCDs): hardware maps
// linear blockID % 8 -> XCD; we remap so each XCD sees a (bn-group x row-stripe)
// sub-grid with bn-fastest order -> B-panels stay L2-resident, A-panels are
// fetched by only XB (not 8) XCDs. Pure perf heuristic; any bijection is correct.
// EPI: 0 = bf16 store; 1 = bf16 store * scale, skip blocks fully above diag;
//      2 = fp32 store + res; 3 = bf16 store relu(acc + bias[n]);
//      4 = fp32 store acc + bias[n] + res
template <int EPI>
__global__ __launch_bounds__(256) void k_gemm_bt(
    const unsigned short* __restrict__ A, const unsigned short* __restrict__ Bt,
    void* __restrict__ Cv, const float* __restrict__ bias, const float* __restrict__ res,
    int K, int lda, int ldb, int ldc,
    long long sA, long long sB, long long sC, float scale, int klimit, int swz) {
    int bn, bm, z;
    if (swz > 0) {
        int GN = gridDim.x, GM = gridDim.y;
        int L = blockIdx.x + GN * (blockIdx.y + GM * blockIdx.z);
        int rows = gridDim.y * gridDim.z;        // (bm,z) merged
        int xcd = L & 7;
        int s = L >> 3;
        int bng = GN / swz;                      // bn per group
        int rpg = rows * swz / 8;                // rows per stripe
        int xg = xcd % swz, yg = xcd / swz;
        int bnl = s % bng;
        int rl = s / bng;
        int row = yg * rpg + rl;
        bn = xg * bng + bnl;
        bm = row % GM;
        z = row / GM;
    } else {
        bn = blockIdx.x; bm = blockIdx.y; z = blockIdx.z;
    }
    if (EPI == 1 && bn > bm) return;  // fully-masked causal block
    A += (long long)z * sA;
    Bt += (long long)z * sB;
    long long coff = (long long)z * sC;
    float* Cf = (float*)Cv;
    unsigned short* Cb = (unsigned short*)Cv;

    __shared__ unsigned short As[128 * 32];  // unpadded: required by global_load_lds lane order
    __shared__ unsigned short Bs[128 * 32];

    int t = threadIdx.x;
    int l = t & 63, w = t >> 6;
    int wm = (w & 1) * 64, wn = (w >> 1) * 64;
    int lr = l & 15, lq = l >> 4;

    f32x4 acc[4][4];
#pragma unroll
    for (int i = 0; i < 4; i++)
#pragma unroll
        for (int j = 0; j < 4; j++) acc[i][j] = (f32x4){0.f, 0.f, 0.f, 0.f};

    int kend = K;
    if (klimit) { int ke = (bm + 1) * 128; kend = ke < K ? ke : K; }

    // staging: wave w covers tile rows [w*32, w*32+32); lane l -> row w*32+(l>>2),
    // k-cols (l&3)*8..+8. LDS chunk base (wave-uniform) + l*16B == row-major 128x32.
    int sr = l >> 2;
    int sc = (l & 3) * 8;
    const unsigned short* gA0 = A + (size_t)(bm * 128 + w * 32 + sr) * lda + sc;
    const unsigned short* gA1 = gA0 + (size_t)16 * lda;
    const unsigned short* gB0 = Bt + (size_t)(bn * 128 + w * 32 + sr) * ldb + sc;
    const unsigned short* gB1 = gB0 + (size_t)16 * ldb;
    unsigned short* lA0 = &As[(w * 32) * 32];
    unsigned short* lA1 = &As[(w * 32 + 16) * 32];
    unsigned short* lB0 = &Bs[(w * 32) * 32];
    unsigned short* lB1 = &Bs[(w * 32 + 16) * 32];

    for (int k0 = 0; k0 < kend; k0 += 32) {
        __syncthreads();  // previous iteration's LDS reads done before overwrite
        gld16(gA0 + k0, lA0);
        gld16(gA1 + k0, lA1);
        gld16(gB0 + k0, lB0);
        gld16(gB1 + k0, lB1);
        __syncthreads();  // vmcnt(0) drained before barrier -> LDS valid
        bf16x8 af[4], bf[4];
#pragma unroll
        for (int i = 0; i < 4; i++)
            af[i] = *(const bf16x8*)(&As[(wm + i * 16 + lr) * 32 + lq * 8]);
#pragma unroll
        for (int j = 0; j < 4; j++)
            bf[j] = *(const bf16x8*)(&Bs[(wn + j * 16 + lr) * 32 + lq * 8]);
#pragma unroll
        for (int i = 0; i < 4; i++)
#pragma unroll
            for (int j = 0; j < 4; j++)
                acc[i][j] = __builtin_amdgcn_mfma_f32_16x16x32_bf16(af[i], bf[j], acc[i][j], 0, 0, 0);
    }

#pragma unroll
    for (int i = 0; i < 4; i++) {
        int mbase = bm * 128 + wm + i * 16 + lq * 4;
#pragma unroll
        for (int j = 0; j < 4; j++) {
            int n = bn * 128 + wn + j * 16 + lr;
#pragma unroll
            for (int r = 0; r < 4; r++) {
                int m = mbase + r;
                float v = acc[i][j][r];
                long long idx = coff + (long long)m * ldc + n;
                if (EPI == 0) {
                    Cb[idx] = f2bf(v);
                } else if (EPI == 1) {
                    Cb[idx] = f2bf(v * scale);
                } else if (EPI == 2) {
                    Cf[idx] = v + res[idx];
                } else if (EPI == 3) {
                    float u = v + bias[n];
                    Cb[idx] = f2bf(u > 0.f ? u : 0.f);
                } else {  // EPI == 4
                    Cf[idx] = v + bias[n] + res[idx];
                }
            }
        }
    }
}

extern "C" void kernel_launch(void* const* d_in, const int* in_sizes, int n_in,
                              void* d_out, int out_size, void* d_ws, size_t ws_size,
                              hipStream_t stream) {
    const float* x      = (const float*)d_in[0];
    const float* Qw     = (const float*)d_in[1];
    const float* Kw     = (const float*)d_in[2];
    const float* Vw     = (const float*)d_in[3];
    const float* w1     = (const float*)d_in[4];
    const float* b1     = (const float*)d_in[5];
    const float* w2     = (const float*)d_in[6];
    const float* b2     = (const float*)d_in[7];
    const float* gamma1 = (const float*)d_in[8];
    const float* beta1  = (const float*)d_in[9];
    const float* gamma2 = (const float*)d_in[10];
    const float* beta2  = (const float*)d_in[11];
    float* out = (float*)d_out;

    char* ws = (char*)d_ws;
    size_t off = 0;
    auto alloc = [&](size_t bytes) -> void* {
        void* p = ws + off;
        off += (bytes + 255) & ~(size_t)255;
        return p;
    };
    const size_t MN = (size_t)B_ * S_ * D_;  // 8.4M elems
    unsigned short* xn     = (unsigned short*)alloc(MN * 2);                     // 16.8MB
    unsigned short* scoreP = (unsigned short*)alloc((size_t)B_ * S_ * S_ * 2);   // 33.6MB, scores->P in place
    unsigned short* qkv    = (unsigned short*)alloc((size_t)B_ * S_ * 3072 * 2); // 50.3MB interleaved Q|K|V
    unsigned short* VT     = (unsigned short*)alloc(MN * 2);                     // 16.8MB
    unsigned short* QKVwT  = (unsigned short*)alloc((size_t)3 * D_ * D_ * 2);    // 6.3MB
    unsigned short* w1T    = (unsigned short*)alloc((size_t)D_ * F_ * 2);        // 8.4MB
    unsigned short* w2T    = (unsigned short*)alloc((size_t)F_ * D_ * 2);        // 8.4MB
    // mid (8192 x 4096 bf16 = 67,108,864 B) overlays qkv+VT (dead after PV).
    unsigned short* mid = qkv;

    dim3 tb(32, 8);
    // weight conversion (transposed so all GEMMs take Bt = N x K)
    k_transpose_w3<<<dim3(D_ / 32, D_ / 32, 3), tb, 0, stream>>>(Qw, Kw, Vw, QKVwT);
    k_transpose_f32_bf16<<<dim3(F_ / 32, D_ / 32), tb, 0, stream>>>(w1, w1T, D_, F_);
    k_transpose_f32_bf16<<<dim3(D_ / 32, F_ / 32), tb, 0, stream>>>(w2, w2T, F_, D_);

    // LN1
    k_layernorm<<<B_ * S_, 256, 0, stream>>>(x, gamma1, beta1, xn);

    // fused QKV projection: M = 8192, N = 3072, K = 1024 -> qkv row-major (ldc 3072)
    const int Mtok = B_ * S_;
    k_gemm_bt<0><<<dim3(3072 / 128, Mtok / 128), 256, 0, stream>>>(
        xn, QKVwT, qkv, nullptr, nullptr, D_, D_, D_, 3072, 0, 0, 0, 1.f, 0, 4);

    // V transpose per batch: (S x D, ld 3072) -> VT (D x S)
    k_transpose_bf16<<<dim3(D_ / 32, S_ / 32, B_), tb, 0, stream>>>(
        qkv + 2048, VT, 3072, S_, (long long)S_ * 3072, (long long)D_ * S_);

    // scores = Q @ K^T / 32 (batched, bf16 out), upper-tri blocks skipped
    k_gemm_bt<1><<<dim3(S_ / 128, S_ / 128, B_), 256, 0, stream>>>(
        qkv, qkv + 1024, scoreP, nullptr, nullptr, D_, 3072, 3072, S_,
        (long long)S_ * 3072, (long long)S_ * 3072, (long long)S_ * S_, 0.03125f, 0, 4);

    // causal softmax in place -> P (bf16)
    k_softmax<<<B_ * S_, 256, 0, stream>>>(scoreP);

    // attn = P @ V + x -> out (fp32); K-loop truncated at diagonal
    k_gemm_bt<2><<<dim3(D_ / 128, S_ / 128, B_), 256, 0, stream>>>(
        scoreP, VT, out, nullptr, x, S_, S_, S_, D_,
        (long long)S_ * S_, (long long)D_ * S_, (long long)S_ * D_, 1.f, 1, 2);

    // LN2 on out -> xn (h)
    k_layernorm<<<B_ * S_, 256, 0, stream>>>(out, gamma2, beta2, xn);

    // mid = relu(h @ w1 + b1) (bf16)
    k_gemm_bt<3><<<dim3(F_ / 128, Mtok / 128), 256, 0, stream>>>(
        xn, w1T, mid, b1, nullptr, D_, D_, D_, F_, 0, 0, 0, 1.f, 0, 4);

    // out = out + mid @ w2 + b2
    k_gemm_bt<4><<<dim3(D_ / 128, Mtok / 128), 256, 0, stream>>>(
        mid, w2T, out, b2, out, F_, F_, F_, D_, 0, 0, 0, 1.f, 0, 2);
}

// Round 6
// 480.849 us; speedup vs baseline: 1.2080x; 1.1700x over previous
//
#include <hip/hip_runtime.h>
#include <hip/hip_bf16.h>

#define B_ 4
#define S_ 2048
#define D_ 1024
#define F_ 4096

typedef short bf16x8 __attribute__((ext_vector_type(8)));
typedef float f32x4 __attribute__((ext_vector_type(4)));

static __device__ __forceinline__ unsigned short f2bf(float f) {
    union { float f; unsigned int u; } v; v.f = f;
    unsigned int u = v.u + 0x7FFF + ((v.u >> 16) & 1);  // RNE
    return (unsigned short)(u >> 16);
}
static __device__ __forceinline__ float bf2f(unsigned short u) {
    union { unsigned int u; float f; } v; v.u = ((unsigned int)u) << 16;
    return v.f;
}

// async global->LDS, 16B per lane. LDS dest is wave-uniform base + lane*16.
typedef const __attribute__((address_space(1))) unsigned int* gp_t;
typedef __attribute__((address_space(3))) unsigned int* lp_t;
static __device__ __forceinline__ void gld16(const unsigned short* g, unsigned short* l) {
    __builtin_amdgcn_global_load_lds((gp_t)g, (lp_t)l, 16, 0, 0);
}

// s_waitcnt with lgkm/exp masked off: vmcnt(N) only (gfx9 encoding:
// vmcnt[3:0]|[15:14], expcnt[6:4]=7, lgkmcnt[11:8]=15)
#define WAIT_VM8() __builtin_amdgcn_s_waitcnt(0x0F78)
#define WAIT_VM0() __builtin_amdgcn_s_waitcnt(0x0F70)

// ---------------- transpose fp32 (R x C) -> bf16 (C x R) ----------------
__global__ __launch_bounds__(256) void k_transpose_f32_bf16(
    const float* __restrict__ in, unsigned short* __restrict__ out, int R, int C) {
    __shared__ float t[32][33];
    int c0 = blockIdx.x * 32, r0 = blockIdx.y * 32;
    int x = threadIdx.x, y = threadIdx.y;  // 32 x 8
#pragma unroll
    for (int i = 0; i < 4; i++)
        t[y + 8 * i][x] = in[(size_t)(r0 + y + 8 * i) * C + c0 + x];
    __syncthreads();
#pragma unroll
    for (int i = 0; i < 4; i++)
        out[(size_t)(c0 + y + 8 * i) * R + r0 + x] = f2bf(t[x][y + 8 * i]);
}

// QKV weight transposes fused: z picks source, writes QKVwT + z*D*D (each D x D)
__global__ __launch_bounds__(256) void k_transpose_w3(
    const float* __restrict__ Qw, const float* __restrict__ Kw, const float* __restrict__ Vw,
    unsigned short* __restrict__ out) {
    __shared__ float t[32][33];
    int z = blockIdx.z;
    const float* in = (z == 0) ? Qw : (z == 1) ? Kw : Vw;
    out += (size_t)z * D_ * D_;
    int c0 = blockIdx.x * 32, r0 = blockIdx.y * 32;
    int x = threadIdx.x, y = threadIdx.y;
#pragma unroll
    for (int i = 0; i < 4; i++)
        t[y + 8 * i][x] = in[(size_t)(r0 + y + 8 * i) * D_ + c0 + x];
    __syncthreads();
#pragma unroll
    for (int i = 0; i < 4; i++)
        out[(size_t)(c0 + y + 8 * i) * D_ + r0 + x] = f2bf(t[x][y + 8 * i]);
}

// ---------------- strided bf16 transpose: in (R x C, ldin, batch szin) -> out (C x R, ldout, szout)
__global__ __launch_bounds__(256) void k_transpose_bf16(
    const unsigned short* __restrict__ in, unsigned short* __restrict__ out,
    int ldin, int ldout, long long szin, long long szout) {
    __shared__ unsigned short t[32][33];
    in += (long long)blockIdx.z * szin;
    out += (long long)blockIdx.z * szout;
    int c0 = blockIdx.x * 32, r0 = blockIdx.y * 32;
    int x = threadIdx.x, y = threadIdx.y;
#pragma unroll
    for (int i = 0; i < 4; i++)
        t[y + 8 * i][x] = in[(size_t)(r0 + y + 8 * i) * ldin + c0 + x];
    __syncthreads();
#pragma unroll
    for (int i = 0; i < 4; i++)
        out[(size_t)(c0 + y + 8 * i) * ldout + r0 + x] = t[x][y + 8 * i];
}

// ---------------- layernorm: fp32 row (D_) -> bf16 row ----------------
__global__ __launch_bounds__(256) void k_layernorm(
    const float* __restrict__ x, const float* __restrict__ gamma,
    const float* __restrict__ beta, unsigned short* __restrict__ out) {
    int row = blockIdx.x;
    int t = threadIdx.x;
    const float* xr = x + (size_t)row * D_;
    float4 v = ((const float4*)xr)[t];
    float s = v.x + v.y + v.z + v.w;
    float q = v.x * v.x + v.y * v.y + v.z * v.z + v.w * v.w;
#pragma unroll
    for (int off = 32; off; off >>= 1) {
        s += __shfl_down(s, off);
        q += __shfl_down(q, off);
    }
    __shared__ float ls[4], lq[4];
    int wv = t >> 6;
    if ((t & 63) == 0) { ls[wv] = s; lq[wv] = q; }
    __syncthreads();
    if (t == 0) {
        float S = ls[0] + ls[1] + ls[2] + ls[3];
        float Q = lq[0] + lq[1] + lq[2] + lq[3];
        float mean = S * (1.0f / D_);
        float var = Q * (1.0f / D_) - mean * mean;
        ls[0] = mean; lq[0] = rsqrtf(var + 1e-5f);
    }
    __syncthreads();
    float mean = ls[0], rstd = lq[0];
    float4 g = ((const float4*)gamma)[t];
    float4 b = ((const float4*)beta)[t];
    ushort4 o;
    o.x = f2bf(g.x * (v.x - mean) * rstd + b.x);
    o.y = f2bf(g.y * (v.y - mean) * rstd + b.y);
    o.z = f2bf(g.z * (v.z - mean) * rstd + b.z);
    o.w = f2bf(g.w * (v.w - mean) * rstd + b.w);
    ((ushort4*)(out + (size_t)row * D_))[t] = o;
}

// ---------------- causal softmax, in-place on bf16 scores rows ----------------
__global__ __launch_bounds__(256) void k_softmax(unsigned short* __restrict__ sp) {
    int r = blockIdx.x;          // global row in [0, B_*S_)
    int i = r & (S_ - 1);        // query index within batch
    unsigned short* row = sp + (size_t)r * S_;
    int t = threadIdx.x;
    int valid = i + 1;
    float vals[8];
    float mx = -1e30f;
#pragma unroll
    for (int k = 0; k < 8; k++) {
        int j = t + k * 256;
        vals[k] = (j < valid) ? bf2f(row[j]) : -1e30f;
        mx = fmaxf(mx, vals[k]);
    }
#pragma unroll
    for (int off = 32; off; off >>= 1) mx = fmaxf(mx, __shfl_xor(mx, off));
    __shared__ float red[4];
    if ((t & 63) == 0) red[t >> 6] = mx;
    __syncthreads();
    mx = fmaxf(fmaxf(red[0], red[1]), fmaxf(red[2], red[3]));
    __syncthreads();
    float e[8];
    float sum = 0.f;
#pragma unroll
    for (int k = 0; k < 8; k++) {
        int j = t + k * 256;
        e[k] = (j < valid) ? __expf(vals[k] - mx) : 0.f;
        sum += e[k];
    }
#pragma unroll
    for (int off = 32; off; off >>= 1) sum += __shfl_xor(sum, off);
    if ((t & 63) == 0) red[t >> 6] = sum;
    __syncthreads();
    sum = red[0] + red[1] + red[2] + red[3];
    float inv = 1.0f / sum;
#pragma unroll
    for (int k = 0; k < 8; k++) {
        int j = t + k * 256;
        row[j] = f2bf(e[k] * inv);
    }
}

// ---------------- GEMM: C = A(MxK) @ Bt(NxK)^T, bf16 in, fp32 accum ----------------
// 128x128 tile, 256 threads / 4 waves. BK=64, double-buffered LDS, async
// prefetch: next tile's 8 global_load_lds stay in flight (vmcnt(8)) across the
// current tile's compute — raw s_barrier avoids __syncthreads' vmcnt(0) drain.
// K (and klimit'd kend) must be a multiple of 64.
// XCD-aware swizzle (swz): remap so each XCD sees a bn-group x row-stripe
// sub-grid (L2 locality; pure perf heuristic, any bijection correct).
// EPI: 0 = bf16 store; 1 = bf16 store * scale, skip blocks fully above diag;
//      2 = fp32 store + res; 3 = bf16 store relu(acc + bias[n]);
//      4 = fp32 store acc + bias[n] + res
template <int EPI>
__global__ __launch_bounds__(256) void k_gemm_bt(
    const unsigned short* __restrict__ A, const unsigned short* __restrict__ Bt,
    void* __restrict__ Cv, const float* __restrict__ bias, const float* __restrict__ res,
    int K, int lda, int ldb, int ldc,
    long long sA, long long sB, long long sC, float scale, int klimit, int swz) {
    int bn, bm, z;
    if (swz > 0) {
        int GN = gridDim.x, GM = gridDim.y;
        int L = blockIdx.x + GN * (blockIdx.y + GM * blockIdx.z);
        int rows = gridDim.y * gridDim.z;        // (bm,z) merged
        int xcd = L & 7;
        int s = L >> 3;
        int bng = GN / swz;                      // bn per group
        int rpg = rows * swz / 8;                // rows per stripe
        int xg = xcd % swz, yg = xcd / swz;
        int bnl = s % bng;
        int rl = s / bng;
        int row = yg * rpg + rl;
        bn = xg * bng + bnl;
        bm = row % GM;
        z = row / GM;
    } else {
        bn = blockIdx.x; bm = blockIdx.y; z = blockIdx.z;
    }
    if (EPI == 1 && bn > bm) return;  // fully-masked causal block
    A += (long long)z * sA;
    Bt += (long long)z * sB;
    long long coff = (long long)z * sC;
    float* Cf = (float*)Cv;
    unsigned short* Cb = (unsigned short*)Cv;

    // [buf][kc][128 rows x 32 k] — per-32k sub-arrays keep the verified
    // gld16 lane map and ds_read offsets (layout identical to the BK=32 tile).
    __shared__ unsigned short As[2][2][128 * 32];  // 32 KB
    __shared__ unsigned short Bs[2][2][128 * 32];  // 32 KB

    int t = threadIdx.x;
    int l = t & 63, w = t >> 6;
    int wm = (w & 1) * 64, wn = (w >> 1) * 64;
    int lr = l & 15, lq = l >> 4;

    f32x4 acc[4][4];
#pragma unroll
    for (int i = 0; i < 4; i++)
#pragma unroll
        for (int j = 0; j < 4; j++) acc[i][j] = (f32x4){0.f, 0.f, 0.f, 0.f};

    int kend = K;
    if (klimit) { int ke = (bm + 1) * 128; kend = ke < K ? ke : K; }

    // staging: per gld16, lane l -> row (l>>2), k-col (l&3)*8 of a 16-row chunk.
    int sr = l >> 2;
    int sc = (l & 3) * 8;
    const unsigned short* gA0 = A + (size_t)(bm * 128 + w * 32 + sr) * lda + sc;
    const unsigned short* gA1 = gA0 + (size_t)16 * lda;
    const unsigned short* gB0 = Bt + (size_t)(bn * 128 + w * 32 + sr) * ldb + sc;
    const unsigned short* gB1 = gB0 + (size_t)16 * ldb;

    auto stage = [&](int buf, int k0) {
#pragma unroll
        for (int kc = 0; kc < 2; kc++) {
            int kk = k0 + kc * 32;
            gld16(gA0 + kk, &As[buf][kc][(w * 32) * 32]);
            gld16(gA1 + kk, &As[buf][kc][(w * 32 + 16) * 32]);
            gld16(gB0 + kk, &Bs[buf][kc][(w * 32) * 32]);
            gld16(gB1 + kk, &Bs[buf][kc][(w * 32 + 16) * 32]);
        }
    };

    int NB = kend >> 6;  // BK=64 iterations
    stage(0, 0);
    for (int it = 0; it < NB; it++) {
        int cur = it & 1;
        if (it + 1 < NB) {
            stage(1 - cur, (it + 1) * 64);  // prefetch next tile (stays in flight)
            WAIT_VM8();                     // current tile's 8 loads complete
        } else {
            WAIT_VM0();
        }
        __builtin_amdgcn_s_barrier();       // all waves: cur buffer full
#pragma unroll
        for (int kc = 0; kc < 2; kc++) {
            bf16x8 af[4], bf[4];
#pragma unroll
            for (int i = 0; i < 4; i++)
                af[i] = *(const bf16x8*)(&As[cur][kc][(wm + i * 16 + lr) * 32 + lq * 8]);
#pragma unroll
            for (int j = 0; j < 4; j++)
                bf[j] = *(const bf16x8*)(&Bs[cur][kc][(wn + j * 16 + lr) * 32 + lq * 8]);
#pragma unroll
            for (int i = 0; i < 4; i++)
#pragma unroll
                for (int j = 0; j < 4; j++)
                    acc[i][j] = __builtin_amdgcn_mfma_f32_16x16x32_bf16(af[i], bf[j], acc[i][j], 0, 0, 0);
        }
        __builtin_amdgcn_s_barrier();       // all waves done reading cur before overwrite
    }

#pragma unroll
    for (int i = 0; i < 4; i++) {
        int mbase = bm * 128 + wm + i * 16 + lq * 4;
#pragma unroll
        for (int j = 0; j < 4; j++) {
            int n = bn * 128 + wn + j * 16 + lr;
#pragma unroll
            for (int r = 0; r < 4; r++) {
                int m = mbase + r;
                float v = acc[i][j][r];
                long long idx = coff + (long long)m * ldc + n;
                if (EPI == 0) {
                    Cb[idx] = f2bf(v);
                } else if (EPI == 1) {
                    Cb[idx] = f2bf(v * scale);
                } else if (EPI == 2) {
                    Cf[idx] = v + res[idx];
                } else if (EPI == 3) {
                    float u = v + bias[n];
                    Cb[idx] = f2bf(u > 0.f ? u : 0.f);
                } else {  // EPI == 4
                    Cf[idx] = v + bias[n] + res[idx];
                }
            }
        }
    }
}

extern "C" void kernel_launch(void* const* d_in, const int* in_sizes, int n_in,
                              void* d_out, int out_size, void* d_ws, size_t ws_size,
                              hipStream_t stream) {
    const float* x      = (const float*)d_in[0];
    const float* Qw     = (const float*)d_in[1];
    const float* Kw     = (const float*)d_in[2];
    const float* Vw     = (const float*)d_in[3];
    const float* w1     = (const float*)d_in[4];
    const float* b1     = (const float*)d_in[5];
    const float* w2     = (const float*)d_in[6];
    const float* b2     = (const float*)d_in[7];
    const float* gamma1 = (const float*)d_in[8];
    const float* beta1  = (const float*)d_in[9];
    const float* gamma2 = (const float*)d_in[10];
    const float* beta2  = (const float*)d_in[11];
    float* out = (float*)d_out;

    char* ws = (char*)d_ws;
    size_t off = 0;
    auto alloc = [&](size_t bytes) -> void* {
        void* p = ws + off;
        off += (bytes + 255) & ~(size_t)255;
        return p;
    };
    const size_t MN = (size_t)B_ * S_ * D_;  // 8.4M elems
    unsigned short* xn     = (unsigned short*)alloc(MN * 2);                     // 16.8MB
    unsigned short* scoreP = (unsigned short*)alloc((size_t)B_ * S_ * S_ * 2);   // 33.6MB, scores->P in place
    unsigned short* qkv    = (unsigned short*)alloc((size_t)B_ * S_ * 3072 * 2); // 50.3MB interleaved Q|K|V
    unsigned short* VT     = (unsigned short*)alloc(MN * 2);                     // 16.8MB
    unsigned short* QKVwT  = (unsigned short*)alloc((size_t)3 * D_ * D_ * 2);    // 6.3MB
    unsigned short* w1T    = (unsigned short*)alloc((size_t)D_ * F_ * 2);        // 8.4MB
    unsigned short* w2T    = (unsigned short*)alloc((size_t)F_ * D_ * 2);        // 8.4MB
    // mid (8192 x 4096 bf16 = 67,108,864 B) overlays qkv+VT (dead after PV).
    unsigned short* mid = qkv;

    dim3 tb(32, 8);
    // weight conversion (transposed so all GEMMs take Bt = N x K)
    k_transpose_w3<<<dim3(D_ / 32, D_ / 32, 3), tb, 0, stream>>>(Qw, Kw, Vw, QKVwT);
    k_transpose_f32_bf16<<<dim3(F_ / 32, D_ / 32), tb, 0, stream>>>(w1, w1T, D_, F_);
    k_transpose_f32_bf16<<<dim3(D_ / 32, F_ / 32), tb, 0, stream>>>(w2, w2T, F_, D_);

    // LN1
    k_layernorm<<<B_ * S_, 256, 0, stream>>>(x, gamma1, beta1, xn);

    // fused QKV projection: M = 8192, N = 3072, K = 1024 -> qkv row-major (ldc 3072)
    const int Mtok = B_ * S_;
    k_gemm_bt<0><<<dim3(3072 / 128, Mtok / 128), 256, 0, stream>>>(
        xn, QKVwT, qkv, nullptr, nullptr, D_, D_, D_, 3072, 0, 0, 0, 1.f, 0, 4);

    // V transpose per batch: (S x D, ld 3072) -> VT (D x S)
    k_transpose_bf16<<<dim3(D_ / 32, S_ / 32, B_), tb, 0, stream>>>(
        qkv + 2048, VT, 3072, S_, (long long)S_ * 3072, (long long)D_ * S_);

    // scores = Q @ K^T / 32 (batched, bf16 out), upper-tri blocks skipped
    k_gemm_bt<1><<<dim3(S_ / 128, S_ / 128, B_), 256, 0, stream>>>(
        qkv, qkv + 1024, scoreP, nullptr, nullptr, D_, 3072, 3072, S_,
        (long long)S_ * 3072, (long long)S_ * 3072, (long long)S_ * S_, 0.03125f, 0, 4);

    // causal softmax in place -> P (bf16)
    k_softmax<<<B_ * S_, 256, 0, stream>>>(scoreP);

    // attn = P @ V + x -> out (fp32); K-loop truncated at diagonal (mult of 64)
    k_gemm_bt<2><<<dim3(D_ / 128, S_ / 128, B_), 256, 0, stream>>>(
        scoreP, VT, out, nullptr, x, S_, S_, S_, D_,
        (long long)S_ * S_, (long long)D_ * S_, (long long)S_ * D_, 1.f, 1, 2);

    // LN2 on out -> xn (h)
    k_layernorm<<<B_ * S_, 256, 0, stream>>>(out, gamma2, beta2, xn);

    // mid = relu(h @ w1 + b1) (bf16)
    k_gemm_bt<3><<<dim3(F_ / 128, Mtok / 128), 256, 0, stream>>>(
        xn, w1T, mid, b1, nullptr, D_, D_, D_, F_, 0, 0, 0, 1.f, 0, 4);

    // out = out + mid @ w2 + b2
    k_gemm_bt<4><<<dim3(D_ / 128, Mtok / 128), 256, 0, stream>>>(
        mid, w2T, out, b2, out, F_, F_, F_, D_, 0, 0, 0, 1.f, 0, 2);
}